// Round 12
// baseline (5994.547 us; speedup 1.0000x reference)
//
#include <hip/hip_runtime.h>
#include <hip/hip_fp16.h>
#include <math.h>

#define NN    6000
#define NPAD  6144
#define NIB   1200
#define NMAXI 80
#define NAVGI 30
#define NBLK  768
#define NTHR  256   // 4 waves/block, 2 rows/wave -> 8 rows/block; 768*8=6144 slots

// float(np.sqrt(np.pi))
#define SQRT_PI_F 1.7724538509055160273f

typedef _Float16 half2_t __attribute__((ext_vector_type(2)));

// Inline erfcx, no libcalls. NR erfcc: erfc(x) ~= t*exp(-x^2+P(t)), t=1/(1+x/2)
// => erfcx(x) = t*exp(P(t)) (exp(x^2) cancels analytically; rel err < 1.2e-7)
__device__ __forceinline__ float erfcx_inl(float y) {
  y = fminf(fmaxf(y, -9.0f), 25.0f);
  const float a   = fabsf(y);
  const float a_s = fminf(a, 5.0f);
  const float t   = 1.0f / (1.0f + 0.5f * a_s);
  const float p   = -1.26551223f + t * (1.00002368f + t * (0.37409196f +
                    t * (0.09678418f + t * (-0.18628806f + t * (0.27886807f +
                    t * (-1.13520398f + t * (1.48851587f + t * (-0.82215223f +
                    t * 0.17087277f))))))));
  const float fsm = t * __expf(p);
  const float a_l = fmaxf(a, 5.0f);
  const float flg = (1.0f / (SQRT_PI_F * a_l)) * (1.0f - 0.5f / (a_l * a_l));
  const float f   = (a <= 5.0f) ? fsm : flg;
  return (y >= 0.0f) ? f : 2.0f * __expf(y * y) - f;
}

__device__ __forceinline__ float dot2acc(unsigned w, unsigned r, float acc) {
#if defined(__has_builtin) && __has_builtin(__builtin_amdgcn_fdot2)
  return __builtin_amdgcn_fdot2(__builtin_bit_cast(half2_t, w),
                                __builtin_bit_cast(half2_t, r), acc, false);
#else
  half2_t wh = __builtin_bit_cast(half2_t, w);
  half2_t rh = __builtin_bit_cast(half2_t, r);
  return acc + (float)wh.x * (float)rh.x + (float)wh.y * (float)rh.y;
#endif
}

__device__ __forceinline__ unsigned pksq(unsigned w) {
  half2_t wh = __builtin_bit_cast(half2_t, w);
  half2_t s  = wh * wh;                 // v_pk_mul_f16
  return __builtin_bit_cast(unsigned, s);
}

// Inline sense-reversing global barrier (proven rounds 6-10, deterministic).
__device__ __forceinline__ void gbar(unsigned* cnt, unsigned* gen, int tid) {
  __syncthreads();
  if (tid == 0) {
    __builtin_amdgcn_fence(__ATOMIC_RELEASE, "agent");
    const unsigned g = __hip_atomic_load(gen, __ATOMIC_RELAXED,
                                         __HIP_MEMORY_SCOPE_AGENT);
    const unsigned old = __hip_atomic_fetch_add(cnt, 1u, __ATOMIC_RELAXED,
                                                __HIP_MEMORY_SCOPE_AGENT);
    if (old == NBLK - 1) {
      __hip_atomic_store(cnt, 0u, __ATOMIC_RELAXED, __HIP_MEMORY_SCOPE_AGENT);
      __hip_atomic_store(gen, g + 1u, __ATOMIC_RELEASE,
                         __HIP_MEMORY_SCOPE_AGENT);
    } else {
      while (__hip_atomic_load(gen, __ATOMIC_RELAXED,
                               __HIP_MEMORY_SCOPE_AGENT) == g)
        __builtin_amdgcn_s_sleep(2);
    }
    __builtin_amdgcn_fence(__ATOMIC_ACQUIRE, "agent");
  }
  __syncthreads();
}

__global__ __launch_bounds__(256) void init_kernel(
    const float* __restrict__ contrast, const float* __restrict__ grat,
    const float* __restrict__ pref, float* __restrict__ g0,
    float* __restrict__ g1, float* __restrict__ meanv,
    float* __restrict__ ctab, float* __restrict__ qn, float* __restrict__ qw,
    unsigned* __restrict__ conv, unsigned* __restrict__ bar)
{
  int t = blockIdx.x * 256 + threadIdx.x;
  if (t < NPAD) { g0[t] = 0.0f; g1[t] = 0.0f; }   // r0 = 0, pads = 0
  if (t < NN) {
    double th = (3.141592653589793 - 0.01) * (double)t / 5999.0;
    ctab[t] = cosf(2.0f * (float)th) - 1.0f;
    float d  = grat[0] - pref[t];
    float cg = (cosf(d * 3.14159265358979323846f / 90.0f) - 1.0f) / 1.0966227112321508f;
    meanv[t] = contrast[0] * 20.0f * expf(cg);
  }
  if (t < NMAXI) conv[t] = 0u;
  if (t < 2)     bar[t]  = 0u;     // barrier cnt / gen (re-zeroed every call)
  // 64-pt Gauss-Legendre nodes/weights via Newton on Legendre recurrence (fp64)
  if (blockIdx.x == 0 && threadIdx.x < 64) {
    int m = threadIdx.x;
    double x = cos(3.141592653589793 * (m + 0.75) / 64.5);
    double p0, p1, dp = 1.0;
    for (int it = 0; it < 60; ++it) {
      p0 = 1.0; p1 = x;
      for (int k = 2; k <= 64; ++k) {
        double p2 = ((2.0 * k - 1.0) * x * p1 - (k - 1.0) * p0) / (double)k;
        p0 = p1; p1 = p2;
      }
      dp = 64.0 * (x * p1 - p0) / (x * x - 1.0);
      double step = p1 / dp;
      x -= step;
      if (fabs(step) < 1e-15) break;
    }
    p0 = 1.0; p1 = x;
    for (int k = 2; k <= 64; ++k) {
      double p2 = ((2.0 * k - 1.0) * x * p1 - (k - 1.0) * p0) / (double)k;
      p0 = p1; p1 = p2;
    }
    dp = 64.0 * (x * p1 - p0) / (x * x - 1.0);
    double wgt = 2.0 / ((1.0 - x * x) * dp * dp);
    qn[63 - m] = (float)x;
    qw[63 - m] = (float)wgt;
  }
}

// Generate one row of W (fp16, padded to NPAD) using 64 lanes of one wave.
__device__ __forceinline__ void gen_row_f16(
    int row, int lane, const float* __restrict__ hyper,
    const float* __restrict__ randu, const float* __restrict__ ctab,
    unsigned short* __restrict__ Wp)
{
  const float cdg = 0.017453292519943295f;   // fp32(pi/180)
  const int ri  = (row < NIB) ? 1 : 0;
  const float eI = hyper[2 + ri], eE = hyper[0 + ri];   // j<NIB : else
  const float pI = hyper[6 + ri], pE = hyper[4 + ri];
  const float wI = cdg * hyper[10 + ri], wE = cdg * hyper[8 + ri];
  const float dI = 4.0f * (wI * wI), dE = 4.0f * (wE * wE);
  const float* ur = randu + (size_t)row * NN;
  unsigned short* wrow = Wp + (size_t)row * NPAD;
#pragma unroll
  for (int k = 0; k < 12; ++k) {
    const int j0 = k * 512 + lane * 8;
    float w[8];
    if (j0 < NN) {   // j0 multiple of 8 and <6000 => j0+7 <= 5999
      const float4 u0 = *reinterpret_cast<const float4*>(ur + j0);
      const float4 u1 = *reinterpret_cast<const float4*>(ur + j0 + 4);
      const float us[8] = {u0.x, u0.y, u0.z, u0.w, u1.x, u1.y, u1.z, u1.w};
#pragma unroll
      for (int q = 0; q < 8; ++q) {
        const int j = j0 + q;
        int idx = j - row; idx += (idx < 0) ? NN : 0;
        const float ct   = ctab[idx];
        const float eff  = (j   < NIB) ? eI : eE;
        const float prob = (j   < NIB) ? pI : pE;
        const float den  = (idx < NIB) ? dI : dE;
        const float Z  = __expf(ct / den);
        const float tt = 32.0f * (prob * Z - us[q]);
        w[q] = eff / (1.0f + __expf(-tt));
      }
    } else {
#pragma unroll
      for (int q = 0; q < 8; ++q) w[q] = 0.0f;
    }
    uint4 pk;
    half2_t h;
    h.x = (_Float16)w[0]; h.y = (_Float16)w[1];
    pk.x = __builtin_bit_cast(unsigned, h);
    h.x = (_Float16)w[2]; h.y = (_Float16)w[3];
    pk.y = __builtin_bit_cast(unsigned, h);
    h.x = (_Float16)w[4]; h.y = (_Float16)w[5];
    pk.z = __builtin_bit_cast(unsigned, h);
    h.x = (_Float16)w[6]; h.y = (_Float16)w[7];
    pk.w = __builtin_bit_cast(unsigned, h);
    *reinterpret_cast<uint4*>(wrow + j0) = pk;
  }
}

// Persistent kernel, W streamed from workspace (fp16, rows padded to 6144).
// 768 blocks x 256 threads (4 waves), 2 rows/wave. Needs 3 blocks/CU
// co-resident (12 waves/CU); __launch_bounds__(256,4) caps VGPR at 128
// so HW capacity is 4 blocks/CU = 1024 >= 768. Host verifies capacity
// via occupancy query BEFORE cooperative launch (round-11 deadlock fix).
__global__ __launch_bounds__(NTHR, 4) void solve_kernel(
    const float* __restrict__ hyper, const float* __restrict__ randu,
    const float* __restrict__ ctab, const float* __restrict__ meanv,
    const float* __restrict__ qn, const float* __restrict__ qw,
    float* __restrict__ g0, float* __restrict__ g1,
    unsigned short* __restrict__ Wp,
    float* __restrict__ blkmax, unsigned* __restrict__ bar,
    float* __restrict__ out)
{
  const int tid  = threadIdx.x;
  const int lane = tid & 63;
  const int wv   = tid >> 6;
  const int rowA = blockIdx.x * 8 + wv * 2;
  const int rowB = rowA + 1;
  const bool act = (rowB < NN);   // rows come in aligned pairs; 6000 % 8 == 0

  __shared__ uint2 rh2[NPAD / 4];     // fp16 r: rh2[i] = r[4i..4i+3]
  __shared__ float wmax[4];
  __shared__ float sflag[NAVGI];

  const float qnl = qn[lane];
  const float qwl = qw[lane];
  const float meanA = act ? meanv[rowA] : 0.0f;
  const float meanB = act ? meanv[rowB] : 0.0f;

  if (act) {
    gen_row_f16(rowA, lane, hyper, randu, ctab, Wp);
    gen_row_f16(rowB, lane, hyper, randu, ctab, Wp);
  }

  const unsigned short* wrA = Wp + (size_t)rowA * NPAD;
  const unsigned short* wrB = Wp + (size_t)rowB * NPAD;

  // ---- fixed-point iteration ----
#pragma unroll 1
  for (int t = 0; t < NMAXI; ++t) {
    const float* rcur = (t & 1) ? g1 : g0;
    float*       rnxt = (t & 1) ? g0 : g1;

    // stage r (fp32 global -> fp16 LDS), uint2 entries (8B stride, 2-way ok)
    {
      const float4* rc4 = reinterpret_cast<const float4*>(rcur);
#pragma unroll
      for (int s = 0; s < 6; ++s) {
        const int i = tid + s * NTHR;
        const float4 v = rc4[i];
        half2_t a, b;
        a.x = (_Float16)v.x; a.y = (_Float16)v.y;
        b.x = (_Float16)v.z; b.y = (_Float16)v.w;
        uint2 p;
        p.x = __builtin_bit_cast(unsigned, a);
        p.y = __builtin_bit_cast(unsigned, b);
        rh2[i] = p;
      }
    }
    __syncthreads();

    float ratioM = 0.0f;
    if (act) {
      // fused W.r and (W*W).r for two rows; W streamed with uint4 loads
      float muA = 0.0f, varA = 0.0f, muB = 0.0f, varB = 0.0f;
#pragma unroll
      for (int k = 0; k < 12; ++k) {
        const int off = k * 512 + lane * 8;
        const uint4 a  = *reinterpret_cast<const uint4*>(wrA + off);
        const uint4 b  = *reinterpret_cast<const uint4*>(wrB + off);
        const uint2 r0 = rh2[k * 128 + lane * 2];
        const uint2 r1 = rh2[k * 128 + lane * 2 + 1];
        muA  = dot2acc(a.x, r0.x, muA);  muA  = dot2acc(a.y, r0.y, muA);
        muA  = dot2acc(a.z, r1.x, muA);  muA  = dot2acc(a.w, r1.y, muA);
        varA = dot2acc(pksq(a.x), r0.x, varA); varA = dot2acc(pksq(a.y), r0.y, varA);
        varA = dot2acc(pksq(a.z), r1.x, varA); varA = dot2acc(pksq(a.w), r1.y, varA);
        muB  = dot2acc(b.x, r0.x, muB);  muB  = dot2acc(b.y, r0.y, muB);
        muB  = dot2acc(b.z, r1.x, muB);  muB  = dot2acc(b.w, r1.y, muB);
        varB = dot2acc(pksq(b.x), r0.x, varB); varB = dot2acc(pksq(b.y), r0.y, varB);
        varB = dot2acc(pksq(b.z), r1.x, varB); varB = dot2acc(pksq(b.w), r1.y, varB);
      }
#pragma unroll
      for (int off = 32; off > 0; off >>= 1) {
        muA  += __shfl_xor(muA, off);
        varA += __shfl_xor(varA, off);
        muB  += __shfl_xor(muB, off);
        varB += __shfl_xor(varB, off);
      }

#pragma unroll
      for (int rr = 0; rr < 2; ++rr) {
        const int   row = rr ? rowB : rowA;
        float mu  = (rr ? muB : muA)  + (rr ? meanB : meanA);
        float var = (rr ? varB : varA) + 25.0f;
        const float sig = sqrtf(var);
        const float uu = (20.0f - mu) / sig;
        const float ll = (10.0f - mu) / sig;
        const float cc = 0.5f * (uu + ll);
        const float hh = 0.5f * (uu - ll);
        const float x = cc + hh * qnl;
        float term    = qwl * erfcx_inl(-x);
#pragma unroll
        for (int off = 32; off > 0; off >>= 1) term += __shfl_xor(term, off);
        const float integ = hh * term;
        const float phiv  = 1.0f / (1.0f + SQRT_PI_F * fmaxf(integ, 0.0f));

        const float rold = rcur[row];           // exact fp32 state
        const float dx   = (phiv - rold) * 0.1f;
        const float rnew = rold + dx;
        ratioM = fmaxf(ratioM, fabsf(dx) / fmaxf(1.0f, fabsf(rnew)));
        if (lane == 0) {
          if (t == NMAXI - 1) out[row] = rnew;
          else                rnxt[row] = rnew;
        }
      }
    }
    if (lane == 0) wmax[wv] = ratioM;
    __syncthreads();
    if (tid == 0) {
      float m = fmaxf(fmaxf(wmax[0], wmax[1]), fmaxf(wmax[2], wmax[3]));
      blkmax[(size_t)t * NBLK + blockIdx.x] = m;
    }
    gbar(bar, bar + 1, tid);
  }

  // ---- convergence epilogue: block 0 reduces blkmax over [50,80) ----
  if (blockIdx.x == 0) {
#pragma unroll
    for (int s = 0; s < 8; ++s) {
      const int t = 50 + wv + 4 * s;
      if (t < NMAXI) {
        float m = 0.0f;   // ratios are >= 0
        for (int p = lane; p < NBLK; p += 64)
          m = fmaxf(m, blkmax[(size_t)t * NBLK + p]);
#pragma unroll
        for (int off = 32; off > 0; off >>= 1)
          m = fmaxf(m, __shfl_xor(m, off));
        if (lane == 0) sflag[t - 50] = (m < 1e-5f) ? 1.0f : 0.0f;
      }
    }
    __syncthreads();
    if (tid == 0) {
      float s = 0.0f;
#pragma unroll
      for (int q = 0; q < NAVGI; ++q) s += sflag[q];
      out[NN] = s / 30.0f;
    }
  }
}

// ---------------- fallback path (non-persistent, fp16 W in ws) -------------
__global__ __launch_bounds__(256) void genw_f16_kernel(
    const float* __restrict__ hyper, const float* __restrict__ randu,
    const float* __restrict__ ctab, unsigned short* __restrict__ Wp)
{
  const int row = blockIdx.x;
  const int lane = (int)threadIdx.x;   // 256 threads; use 8-elem strides
  const float cdg = 0.017453292519943295f;
  const int ri  = (row < NIB) ? 1 : 0;
  const float eI = hyper[2 + ri], eE = hyper[0 + ri];
  const float pI = hyper[6 + ri], pE = hyper[4 + ri];
  const float wI = cdg * hyper[10 + ri], wE = cdg * hyper[8 + ri];
  const float dI = 4.0f * (wI * wI), dE = 4.0f * (wE * wE);
  const float* ur = randu + (size_t)row * NN;
  unsigned short* wrow = Wp + (size_t)row * NPAD;
  for (int j0 = lane * 8; j0 < NPAD; j0 += 2048) {
    float w[8];
    if (j0 < NN) {
      const float4 u0 = *reinterpret_cast<const float4*>(ur + j0);
      const float4 u1 = *reinterpret_cast<const float4*>(ur + j0 + 4);
      const float us[8] = {u0.x, u0.y, u0.z, u0.w, u1.x, u1.y, u1.z, u1.w};
#pragma unroll
      for (int q = 0; q < 8; ++q) {
        const int j = j0 + q;
        int idx = j - row; idx += (idx < 0) ? NN : 0;
        const float ct   = ctab[idx];
        const float eff  = (j   < NIB) ? eI : eE;
        const float prob = (j   < NIB) ? pI : pE;
        const float den  = (idx < NIB) ? dI : dE;
        const float Z  = __expf(ct / den);
        const float tt = 32.0f * (prob * Z - us[q]);
        w[q] = eff / (1.0f + __expf(-tt));
      }
    } else {
#pragma unroll
      for (int q = 0; q < 8; ++q) w[q] = 0.0f;
    }
    uint4 pk;
    half2_t h;
    h.x = (_Float16)w[0]; h.y = (_Float16)w[1];
    pk.x = __builtin_bit_cast(unsigned, h);
    h.x = (_Float16)w[2]; h.y = (_Float16)w[3];
    pk.y = __builtin_bit_cast(unsigned, h);
    h.x = (_Float16)w[4]; h.y = (_Float16)w[5];
    pk.z = __builtin_bit_cast(unsigned, h);
    h.x = (_Float16)w[6]; h.y = (_Float16)w[7];
    pk.w = __builtin_bit_cast(unsigned, h);
    *reinterpret_cast<uint4*>(wrow + j0) = pk;
  }
}

__global__ __launch_bounds__(256) void iter_f16_kernel(
    const unsigned short* __restrict__ Wp, const float* __restrict__ rin,
    float* __restrict__ rout, const float* __restrict__ meanv,
    const float* __restrict__ qn, const float* __restrict__ qw,
    unsigned* __restrict__ convslot)
{
  const int row  = blockIdx.x;
  const int tid  = threadIdx.x;
  const int lane = tid & 63;
  const int wvid = tid >> 6;
  __shared__ float smu[4], svar[4];
  float mu = 0.0f, var = 0.0f;
  const unsigned short* wrow = Wp + (size_t)row * NPAD;
#pragma unroll
  for (int k = 0; k < 3; ++k) {
    const int j0 = k * 2048 + tid * 8;   // rin is padded to 6144 (zeros)
    const uint4 a = *reinterpret_cast<const uint4*>(wrow + j0);
    const float4 r0 = *reinterpret_cast<const float4*>(rin + j0);
    const float4 r1 = *reinterpret_cast<const float4*>(rin + j0 + 4);
    const half2_t h0 = __builtin_bit_cast(half2_t, a.x);
    const half2_t h1 = __builtin_bit_cast(half2_t, a.y);
    const half2_t h2 = __builtin_bit_cast(half2_t, a.z);
    const half2_t h3 = __builtin_bit_cast(half2_t, a.w);
    const float w0 = (float)h0.x, w1 = (float)h0.y;
    const float w2 = (float)h1.x, w3 = (float)h1.y;
    const float w4 = (float)h2.x, w5 = (float)h2.y;
    const float w6 = (float)h3.x, w7 = (float)h3.y;
    mu  += w0 * r0.x + w1 * r0.y + w2 * r0.z + w3 * r0.w
         + w4 * r1.x + w5 * r1.y + w6 * r1.z + w7 * r1.w;
    var += w0 * w0 * r0.x + w1 * w1 * r0.y + w2 * w2 * r0.z + w3 * w3 * r0.w
         + w4 * w4 * r1.x + w5 * w5 * r1.y + w6 * w6 * r1.z + w7 * w7 * r1.w;
  }
#pragma unroll
  for (int off = 32; off > 0; off >>= 1) {
    mu  += __shfl_xor(mu, off);
    var += __shfl_xor(var, off);
  }
  if (lane == 0) { smu[wvid] = mu; svar[wvid] = var; }
  __syncthreads();
  if (tid < 64) {
    mu  = smu[0] + smu[1] + smu[2] + smu[3];
    var = svar[0] + svar[1] + svar[2] + svar[3];
    mu += meanv[row]; var += 25.0f;
    const float sig = sqrtf(var);
    const float uu = (20.0f - mu) / sig;
    const float ll = (10.0f - mu) / sig;
    const float cc = 0.5f * (uu + ll);
    const float hh = 0.5f * (uu - ll);
    const float x = cc + hh * qn[lane];
    float term    = qw[lane] * erfcx_inl(-x);
#pragma unroll
    for (int off = 32; off > 0; off >>= 1) term += __shfl_xor(term, off);
    const float integ = hh * term;
    const float phiv  = 1.0f / (1.0f + SQRT_PI_F * fmaxf(integ, 0.0f));
    const float rold = rin[row];
    const float dx   = (phiv - rold) * 0.1f;
    const float rnew = rold + dx;
    if (lane == 0) {
      rout[row] = rnew;
      const float ratio = fabsf(dx) / fmaxf(1.0f, fabsf(rnew));
      atomicMax(convslot, __float_as_uint(ratio));
    }
  }
}

__global__ __launch_bounds__(256) void final_kernel(
    const float* __restrict__ rfin, const unsigned* __restrict__ conv,
    float* __restrict__ out)
{
  int t = blockIdx.x * 256 + threadIdx.x;
  if (t < NN) out[t] = rfin[t];
  if (t == 6000) {
    float s = 0.0f;
    for (int k = NMAXI - NAVGI; k < NMAXI; ++k)
      s += (__uint_as_float(conv[k]) < 1e-5f) ? 1.0f : 0.0f;
    out[NN] = s / 30.0f;
  }
}

extern "C" void kernel_launch(void* const* d_in, const int* in_sizes, int n_in,
                              void* d_out, int out_size, void* d_ws, size_t ws_size,
                              hipStream_t stream) {
  const float* hyper    = (const float*)d_in[0];
  const float* contrast = (const float*)d_in[1];
  const float* grat     = (const float*)d_in[2];
  const float* pref     = (const float*)d_in[3];
  const float* randu    = (const float*)d_in[4];
  float* out = (float*)d_out;

  char* ws = (char*)d_ws;
  float*    g0     = (float*)(ws + 0);       // 6144 f (r buf A + pad)
  float*    g1     = (float*)(ws + 24576);   // 6144 f (r buf B + pad)
  float*    mn     = (float*)(ws + 49152);   // 6000 f
  float*    ctab   = (float*)(ws + 73152);   // 6000 f
  float*    qn     = (float*)(ws + 97152);   // 64 f
  float*    qw     = (float*)(ws + 97408);   // 64 f
  unsigned* conv   = (unsigned*)(ws + 97664);// 80 u32 (fallback)
  unsigned* bar    = (unsigned*)(ws + 97984);// 2 u32 (barrier cnt/gen)
  float*    blkmax = (float*)(ws + 98304);   // 80*768 f = 245760 B
  unsigned short* Wp = (unsigned short*)(ws + 524288); // fp16 W [6000][6144] = 73.7 MB

  init_kernel<<<24, 256, 0, stream>>>(contrast, grat, pref, g0, g1, mn, ctab,
                                      qn, qw, conv, bar);

  // Cooperative capacity pre-check (round-11 deadlock fix): only take the
  // persistent path if ALL NBLK blocks are guaranteed co-resident.
  bool coop_ok = false;
  {
    int nb = 0;
    hipError_t e = hipOccupancyMaxActiveBlocksPerMultiprocessor(
        &nb, (const void*)solve_kernel, NTHR, 0);
    int cus = 0, dev = 0;
    if (hipGetDevice(&dev) != hipSuccess) dev = 0;
    if (hipDeviceGetAttribute(&cus, hipDeviceAttributeMultiprocessorCount,
                              dev) != hipSuccess || cus <= 0)
      cus = 256;
    coop_ok = (e == hipSuccess) && ((long)nb * cus >= NBLK);
  }

  if (coop_ok) {
    const float* a_hyper = hyper;  const float* a_randu = randu;
    const float* a_ctab  = ctab;   const float* a_mn    = mn;
    const float* a_qn    = qn;     const float* a_qw    = qw;
    float* a_g0 = g0; float* a_g1 = g1;
    unsigned short* a_wp = Wp;
    float* a_bm = blkmax; unsigned* a_bar = bar; float* a_out = out;
    void* args[12] = {&a_hyper, &a_randu, &a_ctab, &a_mn, &a_qn, &a_qw,
                      &a_g0, &a_g1, &a_wp, &a_bm, &a_bar, &a_out};
    hipError_t err = hipLaunchCooperativeKernel(
        (const void*)solve_kernel, dim3(NBLK), dim3(NTHR), args, 0, stream);
    if (err == hipSuccess) return;
  }

  // fallback: non-persistent, fp16 W (73.7 MB, within ws)
  genw_f16_kernel<<<NN, 256, 0, stream>>>(hyper, randu, ctab, Wp);
  float* rb[2] = {g0, g1};
  for (int t = 0; t < NMAXI; ++t) {
    const float* rin = rb[t & 1];
    float*       rou = rb[(t + 1) & 1];
    iter_f16_kernel<<<NN, 256, 0, stream>>>(Wp, rin, rou, mn, qn, qw, conv + t);
  }
  final_kernel<<<24, 256, 0, stream>>>(rb[0], conv, out);
}

// Round 13
// 1993.915 us; speedup vs baseline: 3.0064x; 3.0064x over previous
//
#include <hip/hip_runtime.h>
#include <hip/hip_fp16.h>
#include <math.h>

#define NN    6000
#define NPAD  6144
#define NIB   1200
#define NMAXI 80
#define NAVGI 30
#define NBLK  250
#define NTHR  512   // 8 waves/block, 3 rows/wave (local rows {w, w+8, w+16})
#define NLDSROW 12  // local rows 0..11 live in LDS; 12..23 streamed

#define SQRT_PI_F 1.7724538509055160273f

typedef _Float16 half2_t __attribute__((ext_vector_type(2)));

// Inline erfcx, no libcalls (NR erfcc transform; exp(x^2) cancels analytically)
__device__ __forceinline__ float erfcx_inl(float y) {
  y = fminf(fmaxf(y, -9.0f), 25.0f);
  const float a   = fabsf(y);
  const float a_s = fminf(a, 5.0f);
  const float t   = 1.0f / (1.0f + 0.5f * a_s);
  const float p   = -1.26551223f + t * (1.00002368f + t * (0.37409196f +
                    t * (0.09678418f + t * (-0.18628806f + t * (0.27886807f +
                    t * (-1.13520398f + t * (1.48851587f + t * (-0.82215223f +
                    t * 0.17087277f))))))));
  const float fsm = t * __expf(p);
  const float a_l = fmaxf(a, 5.0f);
  const float flg = (1.0f / (SQRT_PI_F * a_l)) * (1.0f - 0.5f / (a_l * a_l));
  const float f   = (a <= 5.0f) ? fsm : flg;
  return (y >= 0.0f) ? f : 2.0f * __expf(y * y) - f;
}

__device__ __forceinline__ float dot2acc(unsigned w, unsigned r, float acc) {
#if defined(__has_builtin) && __has_builtin(__builtin_amdgcn_fdot2)
  return __builtin_amdgcn_fdot2(__builtin_bit_cast(half2_t, w),
                                __builtin_bit_cast(half2_t, r), acc, false);
#else
  half2_t wh = __builtin_bit_cast(half2_t, w);
  half2_t rh = __builtin_bit_cast(half2_t, r);
  return acc + (float)wh.x * (float)rh.x + (float)wh.y * (float)rh.y;
#endif
}

__device__ __forceinline__ unsigned pksq(unsigned w) {
  half2_t wh = __builtin_bit_cast(half2_t, w);
  half2_t s  = wh * wh;
  return __builtin_bit_cast(unsigned, s);
}

// Inline sense-reversing global barrier (proven rounds 6-12, 250 blocks).
__device__ __forceinline__ void gbar(unsigned* cnt, unsigned* gen, int tid) {
  __syncthreads();
  if (tid == 0) {
    __builtin_amdgcn_fence(__ATOMIC_RELEASE, "agent");
    const unsigned g = __hip_atomic_load(gen, __ATOMIC_RELAXED,
                                         __HIP_MEMORY_SCOPE_AGENT);
    const unsigned old = __hip_atomic_fetch_add(cnt, 1u, __ATOMIC_RELAXED,
                                                __HIP_MEMORY_SCOPE_AGENT);
    if (old == NBLK - 1) {
      __hip_atomic_store(cnt, 0u, __ATOMIC_RELAXED, __HIP_MEMORY_SCOPE_AGENT);
      __hip_atomic_store(gen, g + 1u, __ATOMIC_RELEASE,
                         __HIP_MEMORY_SCOPE_AGENT);
    } else {
      while (__hip_atomic_load(gen, __ATOMIC_RELAXED,
                               __HIP_MEMORY_SCOPE_AGENT) == g)
        __builtin_amdgcn_s_sleep(2);
    }
    __builtin_amdgcn_fence(__ATOMIC_ACQUIRE, "agent");
  }
  __syncthreads();
}

__global__ __launch_bounds__(256) void init_kernel(
    const float* __restrict__ contrast, const float* __restrict__ grat,
    const float* __restrict__ pref, float* __restrict__ g0,
    float* __restrict__ g1, float* __restrict__ meanv,
    float* __restrict__ ctab, float* __restrict__ qn, float* __restrict__ qw,
    unsigned* __restrict__ conv, unsigned* __restrict__ bar)
{
  int t = blockIdx.x * 256 + threadIdx.x;
  if (t < NPAD) { g0[t] = 0.0f; g1[t] = 0.0f; }
  if (t < NN) {
    double th = (3.141592653589793 - 0.01) * (double)t / 5999.0;
    ctab[t] = cosf(2.0f * (float)th) - 1.0f;
    float d  = grat[0] - pref[t];
    float cg = (cosf(d * 3.14159265358979323846f / 90.0f) - 1.0f) / 1.0966227112321508f;
    meanv[t] = contrast[0] * 20.0f * expf(cg);
  }
  if (t < NMAXI) conv[t] = 0u;
  if (t < 2)     bar[t]  = 0u;
  if (blockIdx.x == 0 && threadIdx.x < 64) {
    int m = threadIdx.x;
    double x = cos(3.141592653589793 * (m + 0.75) / 64.5);
    double p0, p1, dp = 1.0;
    for (int it = 0; it < 60; ++it) {
      p0 = 1.0; p1 = x;
      for (int k = 2; k <= 64; ++k) {
        double p2 = ((2.0 * k - 1.0) * x * p1 - (k - 1.0) * p0) / (double)k;
        p0 = p1; p1 = p2;
      }
      dp = 64.0 * (x * p1 - p0) / (x * x - 1.0);
      double step = p1 / dp;
      x -= step;
      if (fabs(step) < 1e-15) break;
    }
    p0 = 1.0; p1 = x;
    for (int k = 2; k <= 64; ++k) {
      double p2 = ((2.0 * k - 1.0) * x * p1 - (k - 1.0) * p0) / (double)k;
      p0 = p1; p1 = p2;
    }
    dp = 64.0 * (x * p1 - p0) / (x * x - 1.0);
    double wgt = 2.0 / ((1.0 - x * x) * dp * dp);
    qn[63 - m] = (float)x;
    qw[63 - m] = (float)wgt;
  }
}

// Persistent kernel. 250 blocks x 512 threads, 24 rows/block.
// W split: local rows 0..11 in LDS (144 KB, written once, read 80x at LDS BW);
// rows 12..23 streamed from Wp global (37 MB device-wide ~ L2-resident).
// Wave w owns local rows {w, w+8, w+16}: mixes LDS + stream so all waves
// contribute memory-level parallelism (r12 lesson).
__global__ __launch_bounds__(NTHR, 2) void solve_kernel(
    const float* __restrict__ hyper, const float* __restrict__ randu,
    const float* __restrict__ ctab, const float* __restrict__ meanv,
    const float* __restrict__ qn, const float* __restrict__ qw,
    float* __restrict__ g0, float* __restrict__ g1,
    unsigned short* __restrict__ Wp,
    float* __restrict__ blkmax, unsigned* __restrict__ bar,
    float* __restrict__ out)
{
  const int tid  = threadIdx.x;
  const int lane = tid & 63;
  const int wv   = tid >> 6;

  const int lrA = wv, lrB = wv + 8, lrC = wv + 16;
  const int rowA = blockIdx.x * 24 + lrA;
  const int rowB = blockIdx.x * 24 + lrB;
  const int rowC = blockIdx.x * 24 + lrC;
  const bool bLds = (lrB < NLDSROW);   // uniform per wave

  extern __shared__ char dynlds[];
  uint4* wlds = (uint4*)dynlds;                       // [12][768] = 147456 B
  uint2* rh2  = (uint2*)(dynlds + 147456);            // [1536]    = 12288 B
  float* wmax = (float*)(dynlds + 147456 + 12288);    // [8]
  float* sflag = wmax + 8;                            // [30]

  const float qnl = qn[lane];
  const float qwl = qw[lane];
  const float meanA = meanv[rowA];
  const float meanB = meanv[rowB];
  const float meanC = meanv[rowC];

  // ---- one-time W generation: pack 8 fp16 (one uint4) for (row, chunk k) --
  const float cdg = 0.017453292519943295f;
  auto genpack = [&](int row, int k) -> uint4 {
    const int ri = (row < NIB) ? 1 : 0;
    const float eI = hyper[2 + ri], eE = hyper[0 + ri];
    const float pI = hyper[6 + ri], pE = hyper[4 + ri];
    const float wI = cdg * hyper[10 + ri], wE = cdg * hyper[8 + ri];
    const float dI = 4.0f * (wI * wI), dE = 4.0f * (wE * wE);
    const int j0 = k * 512 + lane * 8;
    float w[8];
    if (j0 < NN) {
      const float* ur = randu + (size_t)row * NN;
      const float4 u0 = *reinterpret_cast<const float4*>(ur + j0);
      const float4 u1 = *reinterpret_cast<const float4*>(ur + j0 + 4);
      const float us[8] = {u0.x, u0.y, u0.z, u0.w, u1.x, u1.y, u1.z, u1.w};
#pragma unroll
      for (int q = 0; q < 8; ++q) {
        const int j = j0 + q;
        int idx = j - row; idx += (idx < 0) ? NN : 0;
        const float ct   = ctab[idx];
        const float eff  = (j   < NIB) ? eI : eE;
        const float prob = (j   < NIB) ? pI : pE;
        const float den  = (idx < NIB) ? dI : dE;
        const float Z  = __expf(ct / den);
        const float tt = 32.0f * (prob * Z - us[q]);
        w[q] = eff / (1.0f + __expf(-tt));
      }
    } else {
#pragma unroll
      for (int q = 0; q < 8; ++q) w[q] = 0.0f;
    }
    uint4 pk; half2_t h;
    h.x = (_Float16)w[0]; h.y = (_Float16)w[1];
    pk.x = __builtin_bit_cast(unsigned, h);
    h.x = (_Float16)w[2]; h.y = (_Float16)w[3];
    pk.y = __builtin_bit_cast(unsigned, h);
    h.x = (_Float16)w[4]; h.y = (_Float16)w[5];
    pk.z = __builtin_bit_cast(unsigned, h);
    h.x = (_Float16)w[6]; h.y = (_Float16)w[7];
    pk.w = __builtin_bit_cast(unsigned, h);
    return pk;
  };

  // row A: always LDS
  for (int k = 0; k < 12; ++k)
    wlds[(size_t)lrA * 768 + k * 64 + lane] = genpack(rowA, k);
  // row B: LDS for waves 0-3, streamed otherwise
  if (bLds) {
    for (int k = 0; k < 12; ++k)
      wlds[(size_t)lrB * 768 + k * 64 + lane] = genpack(rowB, k);
  } else {
    unsigned short* wr = Wp + (size_t)rowB * NPAD;
    for (int k = 0; k < 12; ++k)
      *reinterpret_cast<uint4*>(wr + k * 512 + lane * 8) = genpack(rowB, k);
  }
  // row C: always streamed
  {
    unsigned short* wr = Wp + (size_t)rowC * NPAD;
    for (int k = 0; k < 12; ++k)
      *reinterpret_cast<uint4*>(wr + k * 512 + lane * 8) = genpack(rowC, k);
  }
  __syncthreads();

  const unsigned short* wrB = Wp + (size_t)rowB * NPAD;
  const unsigned short* wrC = Wp + (size_t)rowC * NPAD;

#define ACC_K(A4, B4, C4, K)                                                  \
  do {                                                                        \
    const uint2 r0 = rh2[(K) * 128 + lane * 2];                               \
    const uint2 r1 = rh2[(K) * 128 + lane * 2 + 1];                           \
    muA  = dot2acc((A4).x, r0.x, muA);  muA  = dot2acc((A4).y, r0.y, muA);    \
    muA  = dot2acc((A4).z, r1.x, muA);  muA  = dot2acc((A4).w, r1.y, muA);    \
    varA = dot2acc(pksq((A4).x), r0.x, varA);                                 \
    varA = dot2acc(pksq((A4).y), r0.y, varA);                                 \
    varA = dot2acc(pksq((A4).z), r1.x, varA);                                 \
    varA = dot2acc(pksq((A4).w), r1.y, varA);                                 \
    muB  = dot2acc((B4).x, r0.x, muB);  muB  = dot2acc((B4).y, r0.y, muB);    \
    muB  = dot2acc((B4).z, r1.x, muB);  muB  = dot2acc((B4).w, r1.y, muB);    \
    varB = dot2acc(pksq((B4).x), r0.x, varB);                                 \
    varB = dot2acc(pksq((B4).y), r0.y, varB);                                 \
    varB = dot2acc(pksq((B4).z), r1.x, varB);                                 \
    varB = dot2acc(pksq((B4).w), r1.y, varB);                                 \
    muC  = dot2acc((C4).x, r0.x, muC);  muC  = dot2acc((C4).y, r0.y, muC);    \
    muC  = dot2acc((C4).z, r1.x, muC);  muC  = dot2acc((C4).w, r1.y, muC);    \
    varC = dot2acc(pksq((C4).x), r0.x, varC);                                 \
    varC = dot2acc(pksq((C4).y), r0.y, varC);                                 \
    varC = dot2acc(pksq((C4).z), r1.x, varC);                                 \
    varC = dot2acc(pksq((C4).w), r1.y, varC);                                 \
  } while (0)

  // ---- fixed-point iteration ----
#pragma unroll 1
  for (int t = 0; t < NMAXI; ++t) {
    const float* rcur = (t & 1) ? g1 : g0;
    float*       rnxt = (t & 1) ? g0 : g1;

    // stage r (fp32 global -> fp16 LDS), uint2 entries
    {
      const float4* rc4 = reinterpret_cast<const float4*>(rcur);
#pragma unroll
      for (int s = 0; s < 3; ++s) {
        const int i = tid + s * NTHR;
        const float4 v = rc4[i];
        half2_t a, b;
        a.x = (_Float16)v.x; a.y = (_Float16)v.y;
        b.x = (_Float16)v.z; b.y = (_Float16)v.w;
        uint2 p;
        p.x = __builtin_bit_cast(unsigned, a);
        p.y = __builtin_bit_cast(unsigned, b);
        rh2[i] = p;
      }
    }
    __syncthreads();

    float muA = 0.0f, varA = 0.0f, muB = 0.0f, varB = 0.0f;
    float muC = 0.0f, varC = 0.0f;
    if (bLds) {
#pragma unroll
      for (int k = 0; k < 12; ++k) {
        const int l4 = k * 64 + lane;
        const uint4 a = wlds[(size_t)lrA * 768 + l4];
        const uint4 b = wlds[(size_t)lrB * 768 + l4];
        const uint4 c = *reinterpret_cast<const uint4*>(wrC + k * 512 + lane * 8);
        ACC_K(a, b, c, k);
      }
    } else {
#pragma unroll
      for (int k = 0; k < 12; ++k) {
        const int l4 = k * 64 + lane;
        const uint4 a = wlds[(size_t)lrA * 768 + l4];
        const uint4 b = *reinterpret_cast<const uint4*>(wrB + k * 512 + lane * 8);
        const uint4 c = *reinterpret_cast<const uint4*>(wrC + k * 512 + lane * 8);
        ACC_K(a, b, c, k);
      }
    }
#pragma unroll
    for (int off = 32; off > 0; off >>= 1) {
      muA  += __shfl_xor(muA, off);
      varA += __shfl_xor(varA, off);
      muB  += __shfl_xor(muB, off);
      varB += __shfl_xor(varB, off);
      muC  += __shfl_xor(muC, off);
      varC += __shfl_xor(varC, off);
    }

    float ratioM = 0.0f;
#pragma unroll
    for (int rr = 0; rr < 3; ++rr) {
      const int   row = (rr == 0) ? rowA : (rr == 1) ? rowB : rowC;
      float mu  = ((rr == 0) ? muA  : (rr == 1) ? muB  : muC)
                + ((rr == 0) ? meanA : (rr == 1) ? meanB : meanC);
      float var = ((rr == 0) ? varA : (rr == 1) ? varB : varC) + 25.0f;
      const float sig = sqrtf(var);
      const float uu = (20.0f - mu) / sig;
      const float ll = (10.0f - mu) / sig;
      const float cc = 0.5f * (uu + ll);
      const float hh = 0.5f * (uu - ll);
      const float x = cc + hh * qnl;
      float term    = qwl * erfcx_inl(-x);
#pragma unroll
      for (int off = 32; off > 0; off >>= 1) term += __shfl_xor(term, off);
      const float integ = hh * term;
      const float phiv  = 1.0f / (1.0f + SQRT_PI_F * fmaxf(integ, 0.0f));

      const float rold = rcur[row];
      const float dx   = (phiv - rold) * 0.1f;
      const float rnew = rold + dx;
      ratioM = fmaxf(ratioM, fabsf(dx) / fmaxf(1.0f, fabsf(rnew)));
      if (lane == 0) {
        if (t == NMAXI - 1) out[row] = rnew;
        else                rnxt[row] = rnew;
      }
    }
    if (lane == 0) wmax[wv] = ratioM;
    __syncthreads();
    if (tid == 0) {
      float m = wmax[0];
#pragma unroll
      for (int q = 1; q < 8; ++q) m = fmaxf(m, wmax[q]);
      blkmax[(size_t)t * NBLK + blockIdx.x] = m;
    }
    gbar(bar, bar + 1, tid);
  }

  // ---- convergence epilogue ----
  if (blockIdx.x == 0) {
#pragma unroll
    for (int s = 0; s < 4; ++s) {
      const int t = 50 + wv + 8 * s;
      if (t < NMAXI) {
        float m = 0.0f;
        for (int p = lane; p < NBLK; p += 64)
          m = fmaxf(m, blkmax[(size_t)t * NBLK + p]);
#pragma unroll
        for (int off = 32; off > 0; off >>= 1)
          m = fmaxf(m, __shfl_xor(m, off));
        if (lane == 0) sflag[t - 50] = (m < 1e-5f) ? 1.0f : 0.0f;
      }
    }
    __syncthreads();
    if (tid == 0) {
      float s = 0.0f;
#pragma unroll
      for (int q = 0; q < NAVGI; ++q) s += sflag[q];
      out[NN] = s / 30.0f;
    }
  }
}

// ---------------- fallback path (non-persistent, fp16 W in ws) -------------
__global__ __launch_bounds__(256) void genw_f16_kernel(
    const float* __restrict__ hyper, const float* __restrict__ randu,
    const float* __restrict__ ctab, unsigned short* __restrict__ Wp)
{
  const int row = blockIdx.x;
  const int lane = (int)threadIdx.x;
  const float cdg = 0.017453292519943295f;
  const int ri  = (row < NIB) ? 1 : 0;
  const float eI = hyper[2 + ri], eE = hyper[0 + ri];
  const float pI = hyper[6 + ri], pE = hyper[4 + ri];
  const float wI = cdg * hyper[10 + ri], wE = cdg * hyper[8 + ri];
  const float dI = 4.0f * (wI * wI), dE = 4.0f * (wE * wE);
  const float* ur = randu + (size_t)row * NN;
  unsigned short* wrow = Wp + (size_t)row * NPAD;
  for (int j0 = lane * 8; j0 < NPAD; j0 += 2048) {
    float w[8];
    if (j0 < NN) {
      const float4 u0 = *reinterpret_cast<const float4*>(ur + j0);
      const float4 u1 = *reinterpret_cast<const float4*>(ur + j0 + 4);
      const float us[8] = {u0.x, u0.y, u0.z, u0.w, u1.x, u1.y, u1.z, u1.w};
#pragma unroll
      for (int q = 0; q < 8; ++q) {
        const int j = j0 + q;
        int idx = j - row; idx += (idx < 0) ? NN : 0;
        const float ct   = ctab[idx];
        const float eff  = (j   < NIB) ? eI : eE;
        const float prob = (j   < NIB) ? pI : pE;
        const float den  = (idx < NIB) ? dI : dE;
        const float Z  = __expf(ct / den);
        const float tt = 32.0f * (prob * Z - us[q]);
        w[q] = eff / (1.0f + __expf(-tt));
      }
    } else {
#pragma unroll
      for (int q = 0; q < 8; ++q) w[q] = 0.0f;
    }
    uint4 pk; half2_t h;
    h.x = (_Float16)w[0]; h.y = (_Float16)w[1];
    pk.x = __builtin_bit_cast(unsigned, h);
    h.x = (_Float16)w[2]; h.y = (_Float16)w[3];
    pk.y = __builtin_bit_cast(unsigned, h);
    h.x = (_Float16)w[4]; h.y = (_Float16)w[5];
    pk.z = __builtin_bit_cast(unsigned, h);
    h.x = (_Float16)w[6]; h.y = (_Float16)w[7];
    pk.w = __builtin_bit_cast(unsigned, h);
    *reinterpret_cast<uint4*>(wrow + j0) = pk;
  }
}

__global__ __launch_bounds__(256) void iter_f16_kernel(
    const unsigned short* __restrict__ Wp, const float* __restrict__ rin,
    float* __restrict__ rout, const float* __restrict__ meanv,
    const float* __restrict__ qn, const float* __restrict__ qw,
    unsigned* __restrict__ convslot)
{
  const int row  = blockIdx.x;
  const int tid  = threadIdx.x;
  const int lane = tid & 63;
  const int wvid = tid >> 6;
  __shared__ float smu[4], svar[4];
  float mu = 0.0f, var = 0.0f;
  const unsigned short* wrow = Wp + (size_t)row * NPAD;
#pragma unroll
  for (int k = 0; k < 3; ++k) {
    const int j0 = k * 2048 + tid * 8;
    const uint4 a = *reinterpret_cast<const uint4*>(wrow + j0);
    const float4 r0 = *reinterpret_cast<const float4*>(rin + j0);
    const float4 r1 = *reinterpret_cast<const float4*>(rin + j0 + 4);
    const half2_t h0 = __builtin_bit_cast(half2_t, a.x);
    const half2_t h1 = __builtin_bit_cast(half2_t, a.y);
    const half2_t h2 = __builtin_bit_cast(half2_t, a.z);
    const half2_t h3 = __builtin_bit_cast(half2_t, a.w);
    const float w0 = (float)h0.x, w1 = (float)h0.y;
    const float w2 = (float)h1.x, w3 = (float)h1.y;
    const float w4 = (float)h2.x, w5 = (float)h2.y;
    const float w6 = (float)h3.x, w7 = (float)h3.y;
    mu  += w0 * r0.x + w1 * r0.y + w2 * r0.z + w3 * r0.w
         + w4 * r1.x + w5 * r1.y + w6 * r1.z + w7 * r1.w;
    var += w0 * w0 * r0.x + w1 * w1 * r0.y + w2 * w2 * r0.z + w3 * w3 * r0.w
         + w4 * w4 * r1.x + w5 * w5 * r1.y + w6 * w6 * r1.z + w7 * w7 * r1.w;
  }
#pragma unroll
  for (int off = 32; off > 0; off >>= 1) {
    mu  += __shfl_xor(mu, off);
    var += __shfl_xor(var, off);
  }
  if (lane == 0) { smu[wvid] = mu; svar[wvid] = var; }
  __syncthreads();
  if (tid < 64) {
    mu  = smu[0] + smu[1] + smu[2] + smu[3];
    var = svar[0] + svar[1] + svar[2] + svar[3];
    mu += meanv[row]; var += 25.0f;
    const float sig = sqrtf(var);
    const float uu = (20.0f - mu) / sig;
    const float ll = (10.0f - mu) / sig;
    const float cc = 0.5f * (uu + ll);
    const float hh = 0.5f * (uu - ll);
    const float x = cc + hh * qn[lane];
    float term    = qw[lane] * erfcx_inl(-x);
#pragma unroll
    for (int off = 32; off > 0; off >>= 1) term += __shfl_xor(term, off);
    const float integ = hh * term;
    const float phiv  = 1.0f / (1.0f + SQRT_PI_F * fmaxf(integ, 0.0f));
    const float rold = rin[row];
    const float dx   = (phiv - rold) * 0.1f;
    const float rnew = rold + dx;
    if (lane == 0) {
      rout[row] = rnew;
      const float ratio = fabsf(dx) / fmaxf(1.0f, fabsf(rnew));
      atomicMax(convslot, __float_as_uint(ratio));
    }
  }
}

__global__ __launch_bounds__(256) void final_kernel(
    const float* __restrict__ rfin, const unsigned* __restrict__ conv,
    float* __restrict__ out)
{
  int t = blockIdx.x * 256 + threadIdx.x;
  if (t < NN) out[t] = rfin[t];
  if (t == 6000) {
    float s = 0.0f;
    for (int k = NMAXI - NAVGI; k < NMAXI; ++k)
      s += (__uint_as_float(conv[k]) < 1e-5f) ? 1.0f : 0.0f;
    out[NN] = s / 30.0f;
  }
}

extern "C" void kernel_launch(void* const* d_in, const int* in_sizes, int n_in,
                              void* d_out, int out_size, void* d_ws, size_t ws_size,
                              hipStream_t stream) {
  const float* hyper    = (const float*)d_in[0];
  const float* contrast = (const float*)d_in[1];
  const float* grat     = (const float*)d_in[2];
  const float* pref     = (const float*)d_in[3];
  const float* randu    = (const float*)d_in[4];
  float* out = (float*)d_out;

  char* ws = (char*)d_ws;
  float*    g0     = (float*)(ws + 0);       // 6144 f
  float*    g1     = (float*)(ws + 24576);   // 6144 f
  float*    mn     = (float*)(ws + 49152);   // 6000 f
  float*    ctab   = (float*)(ws + 73152);   // 6000 f
  float*    qn     = (float*)(ws + 97152);   // 64 f
  float*    qw     = (float*)(ws + 97408);   // 64 f
  unsigned* conv   = (unsigned*)(ws + 97664);// 80 u32 (fallback)
  unsigned* bar    = (unsigned*)(ws + 97984);// 2 u32
  float*    blkmax = (float*)(ws + 98304);   // 80*250 f
  unsigned short* Wp = (unsigned short*)(ws + 524288); // fp16 W [6000][6144]

  const size_t dynBytes = 147456 + 12288 + 32 + 120;   // 159896 <= 160 KiB

  init_kernel<<<24, 256, 0, stream>>>(contrast, grat, pref, g0, g1, mn, ctab,
                                      qn, qw, conv, bar);

  // Opt into >64KB dynamic LDS, then capacity pre-check (deadlock guard).
  bool coop_ok = false;
  {
    hipError_t ea = hipFuncSetAttribute(
        (const void*)solve_kernel,
        hipFuncAttributeMaxDynamicSharedMemorySize, (int)dynBytes);
    int nb = 0;
    hipError_t e = hipOccupancyMaxActiveBlocksPerMultiprocessor(
        &nb, (const void*)solve_kernel, NTHR, dynBytes);
    int cus = 0, dev = 0;
    if (hipGetDevice(&dev) != hipSuccess) dev = 0;
    if (hipDeviceGetAttribute(&cus, hipDeviceAttributeMultiprocessorCount,
                              dev) != hipSuccess || cus <= 0)
      cus = 256;
    coop_ok = (ea == hipSuccess) && (e == hipSuccess) &&
              ((long)nb * cus >= NBLK);
  }

  if (coop_ok) {
    const float* a_hyper = hyper;  const float* a_randu = randu;
    const float* a_ctab  = ctab;   const float* a_mn    = mn;
    const float* a_qn    = qn;     const float* a_qw    = qw;
    float* a_g0 = g0; float* a_g1 = g1;
    unsigned short* a_wp = Wp;
    float* a_bm = blkmax; unsigned* a_bar = bar; float* a_out = out;
    void* args[12] = {&a_hyper, &a_randu, &a_ctab, &a_mn, &a_qn, &a_qw,
                      &a_g0, &a_g1, &a_wp, &a_bm, &a_bar, &a_out};
    hipError_t err = hipLaunchCooperativeKernel(
        (const void*)solve_kernel, dim3(NBLK), dim3(NTHR), args,
        (unsigned)dynBytes, stream);
    if (err == hipSuccess) return;
  }

  // fallback: non-persistent, fp16 W
  genw_f16_kernel<<<NN, 256, 0, stream>>>(hyper, randu, ctab, Wp);
  float* rb[2] = {g0, g1};
  for (int t = 0; t < NMAXI; ++t) {
    const float* rin = rb[t & 1];
    float*       rou = rb[(t + 1) & 1];
    iter_f16_kernel<<<NN, 256, 0, stream>>>(Wp, rin, rou, mn, qn, qw, conv + t);
  }
  final_kernel<<<24, 256, 0, stream>>>(rb[0], conv, out);
}